// Round 8
// baseline (74.223 us; speedup 1.0000x reference)
//
#include <hip/hip_runtime.h>
#include <hip/hip_bf16.h>

// B=4, T=4096, E=512, H=64. out fp32 [B,T,H].
#define Bn 4
#define Tn 4096
#define En 512
#define Hn 64
#define NEGINF -3e38f
// 0.125 (1/sqrt(64)) * log2(e): QK^T output lands in log2 domain
#define QSCALE 0.1803368801f

typedef __attribute__((ext_vector_type(8))) __bf16 bf16x8;
typedef __attribute__((ext_vector_type(4))) __bf16 bf16x4;
typedef __attribute__((ext_vector_type(4))) float f32x4;

#define MFMA16(a, b, c) __builtin_amdgcn_mfma_f32_16x16x32_bf16(a, b, c, 0, 0, 0)

__device__ __forceinline__ unsigned short f2bf(float f) {
    union { float f; unsigned u; } v; v.f = f;
    unsigned r = v.u + 0x7fffu + ((v.u >> 16) & 1u);
    return (unsigned short)(r >> 16);
}
__device__ __forceinline__ unsigned cvtpk(float a, float b) {
    unsigned d;
    asm("v_cvt_pk_bf16_f32 %0, %1, %2" : "=v"(d) : "v"(a), "v"(b));
    return d;
}
__device__ __forceinline__ float exp2fast(float x) {
    float r;
    asm("v_exp_f32 %0, %1" : "=v"(r) : "v"(x));
    return r;
}

// ---------------- kernel 1: W fp32 -> bf16 concat [192][512] ----------------
__global__ void wcvt(const float* __restrict__ Wq, const float* __restrict__ Wk,
                     const float* __restrict__ Wv, unsigned short* __restrict__ Wo) {
    int i = blockIdx.x * 256 + threadIdx.x;      // 0..98303
    int mat = i >> 15;                            // each W is 64*512 = 32768
    int off = i & 32767;
    const float* s = (mat == 0) ? Wq : ((mat == 1) ? Wk : Wv);
    Wo[i] = f2bf(s[off]);
}

// ---------------- kernel 2: fused QKV projection (bf16 MFMA GEMM) -----------
// q16 is pre-scaled by QSCALE so attn's QK^T lands in log2 domain.
__launch_bounds__(256, 2)
__global__ void proj(const float* __restrict__ x, const unsigned short* __restrict__ Wo,
                     unsigned short* __restrict__ q16, unsigned short* __restrict__ k16,
                     unsigned short* __restrict__ vt16) {
    __shared__ unsigned short sA[64 * 72];
    __shared__ unsigned short sW[192 * 72];
    const int tid = threadIdx.x;
    const int w = tid >> 6, lane = tid & 63, r = lane & 15, g = lane >> 4;
    const int row0 = blockIdx.x * 64;

    f32x4 acc[12];
#pragma unroll
    for (int i = 0; i < 12; ++i) acc[i] = (f32x4){0.f, 0.f, 0.f, 0.f};

    for (int k0 = 0; k0 < En; k0 += 64) {
#pragma unroll
        for (int i = 0; i < 2; ++i) {
            int c = tid + i * 256; int arow = c >> 3, kc = (c & 7) * 8;
            const float4* xp = (const float4*)&x[(row0 + arow) * En + k0 + kc];
            float4 f0 = xp[0], f1 = xp[1];
            union { bf16x8 v; unsigned u32[4]; } t;
            t.u32[0] = cvtpk(f0.x, f0.y); t.u32[1] = cvtpk(f0.z, f0.w);
            t.u32[2] = cvtpk(f1.x, f1.y); t.u32[3] = cvtpk(f1.z, f1.w);
            *(bf16x8*)&sA[arow * 72 + kc] = t.v;
        }
#pragma unroll
        for (int i = 0; i < 6; ++i) {
            int c = tid + i * 256; int wrow = c >> 3, kc = (c & 7) * 8;
            bf16x8 wv = *(const bf16x8*)&Wo[wrow * En + k0 + kc];
            *(bf16x8*)&sW[wrow * 72 + kc] = wv;
        }
        __syncthreads();
        bf16x8 a0 = *(bf16x8*)&sA[(w * 16 + r) * 72 + g * 8];
        bf16x8 a1 = *(bf16x8*)&sA[(w * 16 + r) * 72 + 32 + g * 8];
#pragma unroll
        for (int ct = 0; ct < 12; ++ct) {
            bf16x8 b0 = *(bf16x8*)&sW[(ct * 16 + r) * 72 + g * 8];
            bf16x8 b1 = *(bf16x8*)&sW[(ct * 16 + r) * 72 + 32 + g * 8];
            acc[ct] = MFMA16(a0, b0, acc[ct]);
            acc[ct] = MFMA16(a1, b1, acc[ct]);
        }
        __syncthreads();
    }
#pragma unroll
    for (int ct = 0; ct < 12; ++ct) {
        int n = ct * 16 + r;
#pragma unroll
        for (int reg = 0; reg < 4; ++reg) {
            int gr = row0 + w * 16 + g * 4 + reg;
            if (n < 64) {
                q16[gr * 64 + n] = f2bf(acc[ct][reg] * QSCALE);
            } else if (n < 128) {
                k16[gr * 64 + (n - 64)] = f2bf(acc[ct][reg]);
            } else {
                int h = n - 128; int bb = gr >> 12; int t = gr & 4095;
                vt16[((bb * 64 + h) << 12) + t] = f2bf(acc[ct][reg]);
            }
        }
    }
}

// ---------------- kernel 3: causal flash attention ---------------------------
// 512 blocks x 512 thr (8 waves = 2 sq x 4 sk). Block = one 32-row q tile.
// Complementary pairing: bid<256 -> j=127-(idx>>2); bid>=256 -> j=idx>>2;
// blocks c and c+256 share a CU (round-robin) -> uniform 17 iters/CU.
// KV tile 256, SINGLE-buffer LDS (K 32KB | V 32KB) + T14 reg-staging across
// the barrier; oM merge buffer overlaid; 65.5KB -> 2 blocks/CU, 16 waves/CU.
// Softmax in log2 domain (Q pre-scaled); P packed via v_cvt_pk_bf16_f32.
__launch_bounds__(512, 4)
__global__ void attn(const unsigned short* __restrict__ q16, const unsigned short* __restrict__ k16,
                     const unsigned short* __restrict__ vt16, float* __restrict__ out) {
    __shared__ __align__(16) unsigned char lds[65536];   // K 32KB | V 32KB
    __shared__ float mM[2][4][16], lM[2][4][16];
    float* const oMp = (float*)&lds[0];                  // overlay [2sq][4sk][16][64] f32 = 32KB

    const int tid = threadIdx.x;
    const int w = tid >> 6, lane = tid & 63, r = lane & 15, g = lane >> 4;
    const int sq = w >> 2, sk = w & 3;
    const int bid = blockIdx.x;
    const int idx = bid & 255;
    const int b = idx & 3;                               // one batch per XCD
    const int j = (bid >> 8) ? (idx >> 2) : 127 - (idx >> 2);
    const size_t kbase = (size_t)b * Tn;

    const int q0 = j * 32;
    const int nIt = (j + 8) >> 3;                        // ceil(32(j+1)/256)
    const int qrow = b * Tn + q0 + sq * 16;
    const int q = q0 + sq * 16 + r;
    const int qminw = q0 + sq * 16;
    const int qmaxw = qminw + 15;

    const bf16x8 bq0 = *(const bf16x8*)&q16[(qrow + r) * 64 + g * 8];
    const bf16x8 bq1 = *(const bf16x8*)&q16[(qrow + r) * 64 + 32 + g * 8];

    f32x4 o[4];
#pragma unroll
    for (int i = 0; i < 4; ++i) o[i] = (f32x4){0.f, 0.f, 0.f, 0.f};
    float m_ = -1e30f, l_ = 0.f;

    // prologue: stage kv tile 0
    {
#pragma unroll
        for (int p = 0; p < 4; ++p) {
            int row = p * 64 + (tid >> 3), cb = (tid & 7) * 16;
            bf16x8 t = *(const bf16x8*)((const char*)k16 + (kbase + row) * 128 + cb);
            *(bf16x8*)&lds[row * 128 + (cb ^ ((row & 7) << 4))] = t;
        }
#pragma unroll
        for (int p = 0; p < 4; ++p) {
            int h = p * 16 + (tid >> 5), cb = (tid & 31) * 16;
            bf16x8 t = *(const bf16x8*)((const char*)vt16 + ((size_t)(b * 64 + h)) * 8192 + cb);
            *(bf16x8*)&lds[32768 + h * 512 + (cb ^ ((h & 7) << 4))] = t;
        }
    }
    __syncthreads();

    for (int it = 0; it < nIt; ++it) {
        const int kv0 = it * 256;
        const bool more = (it + 1 < nIt);
        const bool live = (kv0 + sk * 64 <= qmaxw);
        bf16x8 stK[4], stV[4];
        int sdK[4], sdV[4];
        // T14a: issue next-tile K loads
        if (more) {
            int nkv = kv0 + 256;
#pragma unroll
            for (int p = 0; p < 4; ++p) {
                int row = p * 64 + (tid >> 3), cb = (tid & 7) * 16;
                stK[p] = *(const bf16x8*)((const char*)k16 + (kbase + nkv + row) * 128 + cb);
                sdK[p] = row * 128 + (cb ^ ((row & 7) << 4));
            }
        }
        f32x4 s[4];
        if (live) {
            const unsigned char* K = &lds[0];
            __builtin_amdgcn_s_setprio(1);
#pragma unroll
            for (int ct = 0; ct < 4; ++ct) {
                int row = sk * 64 + ct * 16 + r;
                int base = row * 128, sw = (row & 7) << 4;
                bf16x8 ak0 = *(const bf16x8*)&K[base + ((g * 16) ^ sw)];
                bf16x8 ak1 = *(const bf16x8*)&K[base + ((64 + g * 16) ^ sw)];
                f32x4 t = (f32x4){0.f, 0.f, 0.f, 0.f};
                t = MFMA16(ak0, bq0, t);
                t = MFMA16(ak1, bq1, t);
                s[ct] = t;
            }
            __builtin_amdgcn_s_setprio(0);
        }
        // T14b: issue next-tile V loads (hide under softmax+PV)
        if (more) {
            int nkv = kv0 + 256;
#pragma unroll
            for (int p = 0; p < 4; ++p) {
                int h = p * 16 + (tid >> 5), cb = (tid & 31) * 16;
                stV[p] = *(const bf16x8*)((const char*)vt16 + ((size_t)(b * 64 + h)) * 8192 + (size_t)nkv * 2 + cb);
                sdV[p] = 32768 + h * 512 + (cb ^ ((h & 7) << 4));
            }
        }
        if (live) {
            const unsigned char* V = &lds[32768];
            // mask (no scale: Q pre-scaled into log2 domain)
            if (kv0 + sk * 64 + 63 > qminw) {
#pragma unroll
                for (int ct = 0; ct < 4; ++ct)
#pragma unroll
                    for (int reg = 0; reg < 4; ++reg) {
                        int kv = kv0 + sk * 64 + ct * 16 + g * 4 + reg;
                        if (kv > q) s[ct][reg] = NEGINF;
                    }
            }
            // row max: in-lane tree + 2 shuffles
            float a0 = fmaxf(fmaxf(s[0][0], s[0][1]), fmaxf(s[0][2], s[0][3]));
            float a1 = fmaxf(fmaxf(s[1][0], s[1][1]), fmaxf(s[1][2], s[1][3]));
            float a2 = fmaxf(fmaxf(s[2][0], s[2][1]), fmaxf(s[2][2], s[2][3]));
            float a3 = fmaxf(fmaxf(s[3][0], s[3][1]), fmaxf(s[3][2], s[3][3]));
            float mx = fmaxf(fmaxf(a0, a1), fmaxf(a2, a3));
            mx = fmaxf(mx, __shfl_xor(mx, 16));
            mx = fmaxf(mx, __shfl_xor(mx, 32));
            // defer-max (log2 units): P bounded by 2^8
            if (__any(mx > m_ + 8.0f)) {
                float mn = fmaxf(m_, mx);
                float corr = exp2fast(m_ - mn);
                m_ = mn;
                l_ *= corr;
                float cq[4];
#pragma unroll
                for (int reg = 0; reg < 4; ++reg) cq[reg] = __shfl(corr, g * 4 + reg);
#pragma unroll
                for (int cth = 0; cth < 4; ++cth)
#pragma unroll
                    for (int reg = 0; reg < 4; ++reg) o[cth][reg] *= cq[reg];
            }
#pragma unroll
            for (int ct = 0; ct < 4; ++ct)
#pragma unroll
                for (int reg = 0; reg < 4; ++reg)
                    s[ct][reg] = exp2fast(s[ct][reg] - m_);
            float sm = ((s[0][0] + s[0][1]) + (s[0][2] + s[0][3])) +
                       ((s[1][0] + s[1][1]) + (s[1][2] + s[1][3])) +
                       ((s[2][0] + s[2][1]) + (s[2][2] + s[2][3])) +
                       ((s[3][0] + s[3][1]) + (s[3][2] + s[3][3]));
            sm += __shfl_xor(sm, 16);
            sm += __shfl_xor(sm, 32);
            l_ += sm;
            // pack P via cvt_pk: frag kf slot j <- s[kf*2+(j>>2)][j&3]
            union { bf16x8 v; unsigned u32[4]; } pk[2];
#pragma unroll
            for (int kf = 0; kf < 2; ++kf) {
                pk[kf].u32[0] = cvtpk(s[kf * 2][0], s[kf * 2][1]);
                pk[kf].u32[1] = cvtpk(s[kf * 2][2], s[kf * 2][3]);
                pk[kf].u32[2] = cvtpk(s[kf * 2 + 1][0], s[kf * 2 + 1][1]);
                pk[kf].u32[3] = cvtpk(s[kf * 2 + 1][2], s[kf * 2 + 1][3]);
            }
            // PV: V B-frag with matching k-bijection
            __builtin_amdgcn_s_setprio(1);
#pragma unroll
            for (int cth = 0; cth < 4; ++cth) {
                int h = cth * 16 + r;
                int vb = h * 512, sw2 = (h & 7) << 4;
#pragma unroll
                for (int kf = 0; kf < 2; ++kf) {
                    int off = sk * 128 + kf * 64 + g * 8;
                    union { bf16x8 v; bf16x4 h4[2]; } vv;
                    vv.h4[0] = *(const bf16x4*)&V[vb + (off ^ sw2)];
                    vv.h4[1] = *(const bf16x4*)&V[vb + ((off + 32) ^ sw2)];
                    o[cth] = MFMA16(pk[kf].v, vv.v, o[cth]);
                }
            }
            __builtin_amdgcn_s_setprio(0);
        }
        __syncthreads();                 // all reads of this tile done
        if (more) {
#pragma unroll
            for (int p = 0; p < 4; ++p) *(bf16x8*)&lds[sdK[p]] = stK[p];
#pragma unroll
            for (int p = 0; p < 4; ++p) *(bf16x8*)&lds[sdV[p]] = stV[p];
            __syncthreads();             // next tile ready
        }
    }

    // ---- partials to LDS (oM overlays stage buffer; loop done) ----
#pragma unroll
    for (int cth = 0; cth < 4; ++cth)
#pragma unroll
        for (int reg = 0; reg < 4; ++reg)
            oMp[(((sq * 4 + sk) * 16) + g * 4 + reg) * 64 + cth * 16 + r] = o[cth][reg];
    if (lane < 16) {
        mM[sq][sk][lane] = m_;
        lM[sq][sk][lane] = l_;
    }
    __syncthreads();

    // ---- merge 4-way across sk; wave (sq,sk) takes rows sk*4+g ----
    {
        int rr = sk * 4 + g;
        float m0 = mM[sq][0][rr], m1 = mM[sq][1][rr], m2 = mM[sq][2][rr], m3 = mM[sq][3][rr];
        float M = fmaxf(fmaxf(m0, m1), fmaxf(m2, m3));
        float w0 = exp2fast(m0 - M), w1 = exp2fast(m1 - M);
        float w2 = exp2fast(m2 - M), w3 = exp2fast(m3 - M);
        float L = w0 * lM[sq][0][rr] + w1 * lM[sq][1][rr] + w2 * lM[sq][2][rr] + w3 * lM[sq][3][rr];
        float inv = 1.0f / L;
        int orow = b * Tn + q0 + sq * 16 + rr;
#pragma unroll
        for (int jj = 0; jj < 4; ++jj) {
            int col = r + 16 * jj;
            float val = w0 * oMp[((sq * 4 + 0) * 16 + rr) * 64 + col] +
                        w1 * oMp[((sq * 4 + 1) * 16 + rr) * 64 + col] +
                        w2 * oMp[((sq * 4 + 2) * 16 + rr) * 64 + col] +
                        w3 * oMp[((sq * 4 + 3) * 16 + rr) * 64 + col];
            out[orow * 64 + col] = val * inv;
        }
    }
}

extern "C" void kernel_launch(void* const* d_in, const int* in_sizes, int n_in,
                              void* d_out, int out_size, void* d_ws, size_t ws_size,
                              hipStream_t stream) {
    const float* x  = (const float*)d_in[0];
    const float* Wq = (const float*)d_in[1];
    const float* Wk = (const float*)d_in[2];
    const float* Wv = (const float*)d_in[3];
    float* out = (float*)d_out;
    char* ws = (char*)d_ws;

    unsigned short* Wo  = (unsigned short*)ws;                       // 192*512*2   = 196608 B
    unsigned short* q16 = (unsigned short*)(ws + 196608);            // 16384*64*2  = 2 MiB
    unsigned short* k16 = (unsigned short*)(ws + 196608 + 2097152);
    unsigned short* v16 = (unsigned short*)(ws + 196608 + 2 * 2097152);

    hipLaunchKernelGGL(wcvt, dim3(384), dim3(256), 0, stream, Wq, Wk, Wv, Wo);
    hipLaunchKernelGGL(proj, dim3(256), dim3(256), 0, stream, x, Wo, q16, k16, v16);
    hipLaunchKernelGGL(attn, dim3(512), dim3(512), 0, stream, q16, k16, v16, out);
}

// Round 9
// 67.240 us; speedup vs baseline: 1.1039x; 1.1039x over previous
//
#include <hip/hip_runtime.h>
#include <hip/hip_bf16.h>

// B=4, T=4096, E=512, H=64. out fp32 [B,T,H].
#define Bn 4
#define Tn 4096
#define En 512
#define Hn 64
#define NEGINF -3e38f
// 0.125 (1/sqrt(64)) * log2(e): QK^T output lands in log2 domain
#define QSCALE 0.1803368801f

typedef __attribute__((ext_vector_type(8))) __bf16 bf16x8;
typedef __attribute__((ext_vector_type(4))) __bf16 bf16x4;
typedef __attribute__((ext_vector_type(4))) float f32x4;

#define MFMA16(a, b, c) __builtin_amdgcn_mfma_f32_16x16x32_bf16(a, b, c, 0, 0, 0)

__device__ __forceinline__ unsigned short f2bf(float f) {
    union { float f; unsigned u; } v; v.f = f;
    unsigned r = v.u + 0x7fffu + ((v.u >> 16) & 1u);
    return (unsigned short)(r >> 16);
}
__device__ __forceinline__ unsigned cvtpk(float a, float b) {
    unsigned d;
    asm("v_cvt_pk_bf16_f32 %0, %1, %2" : "=v"(d) : "v"(a), "v"(b));
    return d;
}
__device__ __forceinline__ float exp2fast(float x) {
    float r;
    asm("v_exp_f32 %0, %1" : "=v"(r) : "v"(x));
    return r;
}

// ---------------- kernel 1: W fp32 -> bf16 concat [192][512] ----------------
__global__ void wcvt(const float* __restrict__ Wq, const float* __restrict__ Wk,
                     const float* __restrict__ Wv, unsigned short* __restrict__ Wo) {
    int i = blockIdx.x * 256 + threadIdx.x;      // 0..98303
    int mat = i >> 15;                            // each W is 64*512 = 32768
    int off = i & 32767;
    const float* s = (mat == 0) ? Wq : ((mat == 1) ? Wk : Wv);
    Wo[i] = f2bf(s[off]);
}

// ---------------- kernel 2: fused QKV projection (bf16 MFMA GEMM) -----------
// q16 is pre-scaled by QSCALE so attn's QK^T lands in log2 domain.
__launch_bounds__(256, 2)
__global__ void proj(const float* __restrict__ x, const unsigned short* __restrict__ Wo,
                     unsigned short* __restrict__ q16, unsigned short* __restrict__ k16,
                     unsigned short* __restrict__ vt16) {
    __shared__ unsigned short sA[64 * 72];
    __shared__ unsigned short sW[192 * 72];
    const int tid = threadIdx.x;
    const int w = tid >> 6, lane = tid & 63, r = lane & 15, g = lane >> 4;
    const int row0 = blockIdx.x * 64;

    f32x4 acc[12];
#pragma unroll
    for (int i = 0; i < 12; ++i) acc[i] = (f32x4){0.f, 0.f, 0.f, 0.f};

    for (int k0 = 0; k0 < En; k0 += 64) {
#pragma unroll
        for (int i = 0; i < 2; ++i) {
            int c = tid + i * 256; int arow = c >> 3, kc = (c & 7) * 8;
            const float4* xp = (const float4*)&x[(row0 + arow) * En + k0 + kc];
            float4 f0 = xp[0], f1 = xp[1];
            union { bf16x8 v; unsigned u32[4]; } t;
            t.u32[0] = cvtpk(f0.x, f0.y); t.u32[1] = cvtpk(f0.z, f0.w);
            t.u32[2] = cvtpk(f1.x, f1.y); t.u32[3] = cvtpk(f1.z, f1.w);
            *(bf16x8*)&sA[arow * 72 + kc] = t.v;
        }
#pragma unroll
        for (int i = 0; i < 6; ++i) {
            int c = tid + i * 256; int wrow = c >> 3, kc = (c & 7) * 8;
            bf16x8 wv = *(const bf16x8*)&Wo[wrow * En + k0 + kc];
            *(bf16x8*)&sW[wrow * 72 + kc] = wv;
        }
        __syncthreads();
        bf16x8 a0 = *(bf16x8*)&sA[(w * 16 + r) * 72 + g * 8];
        bf16x8 a1 = *(bf16x8*)&sA[(w * 16 + r) * 72 + 32 + g * 8];
#pragma unroll
        for (int ct = 0; ct < 12; ++ct) {
            bf16x8 b0 = *(bf16x8*)&sW[(ct * 16 + r) * 72 + g * 8];
            bf16x8 b1 = *(bf16x8*)&sW[(ct * 16 + r) * 72 + 32 + g * 8];
            acc[ct] = MFMA16(a0, b0, acc[ct]);
            acc[ct] = MFMA16(a1, b1, acc[ct]);
        }
        __syncthreads();
    }
#pragma unroll
    for (int ct = 0; ct < 12; ++ct) {
        int n = ct * 16 + r;
#pragma unroll
        for (int reg = 0; reg < 4; ++reg) {
            int gr = row0 + w * 16 + g * 4 + reg;
            if (n < 64) {
                q16[gr * 64 + n] = f2bf(acc[ct][reg] * QSCALE);
            } else if (n < 128) {
                k16[gr * 64 + (n - 64)] = f2bf(acc[ct][reg]);
            } else {
                int h = n - 128; int bb = gr >> 12; int t = gr & 4095;
                vt16[((bb * 64 + h) << 12) + t] = f2bf(acc[ct][reg]);
            }
        }
    }
}

// ---------------- kernel 3: causal flash attention ---------------------------
// 512 blocks x 512 thr (8 waves = 2 sq x 4 sk). Block = one 32-row q tile.
// Complementary pairing: bid<256 -> j=127-(idx>>2); bid>=256 -> j=idx>>2;
// blocks c and c+256 share a CU (round-robin) -> uniform 17 iters/CU.
// KV tile 256, SINGLE-buffer LDS (K 32KB | V 32KB) + T14 reg-staging across
// the barrier; oM merge buffer overlaid; 65.5KB -> 2 blocks/CU, 16 waves/CU.
// Softmax in log2 domain (Q pre-scaled); P packed via v_cvt_pk_bf16_f32.
// launch_bounds(512,2): VGPR cap 256 -- (512,4) capped VGPR at 64 and spilled
// (round 8: FETCH 15MB / WRITE 25MB of scratch traffic).
__launch_bounds__(512, 2)
__global__ void attn(const unsigned short* __restrict__ q16, const unsigned short* __restrict__ k16,
                     const unsigned short* __restrict__ vt16, float* __restrict__ out) {
    __shared__ __align__(16) unsigned char lds[65536];   // K 32KB | V 32KB
    __shared__ float mM[2][4][16], lM[2][4][16];
    float* const oMp = (float*)&lds[0];                  // overlay [2sq][4sk][16][64] f32 = 32KB

    const int tid = threadIdx.x;
    const int w = tid >> 6, lane = tid & 63, r = lane & 15, g = lane >> 4;
    const int sq = w >> 2, sk = w & 3;
    const int bid = blockIdx.x;
    const int idx = bid & 255;
    const int b = idx & 3;                               // one batch per XCD
    const int j = (bid >> 8) ? (idx >> 2) : 127 - (idx >> 2);
    const size_t kbase = (size_t)b * Tn;

    const int q0 = j * 32;
    const int nIt = (j + 8) >> 3;                        // ceil(32(j+1)/256)
    const int qrow = b * Tn + q0 + sq * 16;
    const int q = q0 + sq * 16 + r;
    const int qminw = q0 + sq * 16;
    const int qmaxw = qminw + 15;

    const bf16x8 bq0 = *(const bf16x8*)&q16[(qrow + r) * 64 + g * 8];
    const bf16x8 bq1 = *(const bf16x8*)&q16[(qrow + r) * 64 + 32 + g * 8];

    f32x4 o[4];
#pragma unroll
    for (int i = 0; i < 4; ++i) o[i] = (f32x4){0.f, 0.f, 0.f, 0.f};
    float m_ = -1e30f, l_ = 0.f;

    // prologue: stage kv tile 0
    {
#pragma unroll
        for (int p = 0; p < 4; ++p) {
            int row = p * 64 + (tid >> 3), cb = (tid & 7) * 16;
            bf16x8 t = *(const bf16x8*)((const char*)k16 + (kbase + row) * 128 + cb);
            *(bf16x8*)&lds[row * 128 + (cb ^ ((row & 7) << 4))] = t;
        }
#pragma unroll
        for (int p = 0; p < 4; ++p) {
            int h = p * 16 + (tid >> 5), cb = (tid & 31) * 16;
            bf16x8 t = *(const bf16x8*)((const char*)vt16 + ((size_t)(b * 64 + h)) * 8192 + cb);
            *(bf16x8*)&lds[32768 + h * 512 + (cb ^ ((h & 7) << 4))] = t;
        }
    }
    __syncthreads();

    for (int it = 0; it < nIt; ++it) {
        const int kv0 = it * 256;
        const bool more = (it + 1 < nIt);
        const bool live = (kv0 + sk * 64 <= qmaxw);
        bf16x8 stK[4], stV[4];
        int sdK[4], sdV[4];
        // T14a: issue next-tile K loads
        if (more) {
            int nkv = kv0 + 256;
#pragma unroll
            for (int p = 0; p < 4; ++p) {
                int row = p * 64 + (tid >> 3), cb = (tid & 7) * 16;
                stK[p] = *(const bf16x8*)((const char*)k16 + (kbase + nkv + row) * 128 + cb);
                sdK[p] = row * 128 + (cb ^ ((row & 7) << 4));
            }
        }
        f32x4 s[4];
        if (live) {
            const unsigned char* K = &lds[0];
            __builtin_amdgcn_s_setprio(1);
#pragma unroll
            for (int ct = 0; ct < 4; ++ct) {
                int row = sk * 64 + ct * 16 + r;
                int base = row * 128, sw = (row & 7) << 4;
                bf16x8 ak0 = *(const bf16x8*)&K[base + ((g * 16) ^ sw)];
                bf16x8 ak1 = *(const bf16x8*)&K[base + ((64 + g * 16) ^ sw)];
                f32x4 t = (f32x4){0.f, 0.f, 0.f, 0.f};
                t = MFMA16(ak0, bq0, t);
                t = MFMA16(ak1, bq1, t);
                s[ct] = t;
            }
            __builtin_amdgcn_s_setprio(0);
        }
        // T14b: issue next-tile V loads (hide under softmax+PV)
        if (more) {
            int nkv = kv0 + 256;
#pragma unroll
            for (int p = 0; p < 4; ++p) {
                int h = p * 16 + (tid >> 5), cb = (tid & 31) * 16;
                stV[p] = *(const bf16x8*)((const char*)vt16 + ((size_t)(b * 64 + h)) * 8192 + (size_t)nkv * 2 + cb);
                sdV[p] = 32768 + h * 512 + (cb ^ ((h & 7) << 4));
            }
        }
        if (live) {
            const unsigned char* V = &lds[32768];
            // mask (no scale: Q pre-scaled into log2 domain)
            if (kv0 + sk * 64 + 63 > qminw) {
#pragma unroll
                for (int ct = 0; ct < 4; ++ct)
#pragma unroll
                    for (int reg = 0; reg < 4; ++reg) {
                        int kv = kv0 + sk * 64 + ct * 16 + g * 4 + reg;
                        if (kv > q) s[ct][reg] = NEGINF;
                    }
            }
            // row max: in-lane tree + 2 shuffles
            float a0 = fmaxf(fmaxf(s[0][0], s[0][1]), fmaxf(s[0][2], s[0][3]));
            float a1 = fmaxf(fmaxf(s[1][0], s[1][1]), fmaxf(s[1][2], s[1][3]));
            float a2 = fmaxf(fmaxf(s[2][0], s[2][1]), fmaxf(s[2][2], s[2][3]));
            float a3 = fmaxf(fmaxf(s[3][0], s[3][1]), fmaxf(s[3][2], s[3][3]));
            float mx = fmaxf(fmaxf(a0, a1), fmaxf(a2, a3));
            mx = fmaxf(mx, __shfl_xor(mx, 16));
            mx = fmaxf(mx, __shfl_xor(mx, 32));
            // defer-max (log2 units): P bounded by 2^8
            if (__any(mx > m_ + 8.0f)) {
                float mn = fmaxf(m_, mx);
                float corr = exp2fast(m_ - mn);
                m_ = mn;
                l_ *= corr;
                float cq[4];
#pragma unroll
                for (int reg = 0; reg < 4; ++reg) cq[reg] = __shfl(corr, g * 4 + reg);
#pragma unroll
                for (int cth = 0; cth < 4; ++cth)
#pragma unroll
                    for (int reg = 0; reg < 4; ++reg) o[cth][reg] *= cq[reg];
            }
#pragma unroll
            for (int ct = 0; ct < 4; ++ct)
#pragma unroll
                for (int reg = 0; reg < 4; ++reg)
                    s[ct][reg] = exp2fast(s[ct][reg] - m_);
            float sm = ((s[0][0] + s[0][1]) + (s[0][2] + s[0][3])) +
                       ((s[1][0] + s[1][1]) + (s[1][2] + s[1][3])) +
                       ((s[2][0] + s[2][1]) + (s[2][2] + s[2][3])) +
                       ((s[3][0] + s[3][1]) + (s[3][2] + s[3][3]));
            sm += __shfl_xor(sm, 16);
            sm += __shfl_xor(sm, 32);
            l_ += sm;
            // pack P via cvt_pk: frag kf slot j <- s[kf*2+(j>>2)][j&3]
            union { bf16x8 v; unsigned u32[4]; } pk[2];
#pragma unroll
            for (int kf = 0; kf < 2; ++kf) {
                pk[kf].u32[0] = cvtpk(s[kf * 2][0], s[kf * 2][1]);
                pk[kf].u32[1] = cvtpk(s[kf * 2][2], s[kf * 2][3]);
                pk[kf].u32[2] = cvtpk(s[kf * 2 + 1][0], s[kf * 2 + 1][1]);
                pk[kf].u32[3] = cvtpk(s[kf * 2 + 1][2], s[kf * 2 + 1][3]);
            }
            // PV: V B-frag with matching k-bijection
            __builtin_amdgcn_s_setprio(1);
#pragma unroll
            for (int cth = 0; cth < 4; ++cth) {
                int h = cth * 16 + r;
                int vb = h * 512, sw2 = (h & 7) << 4;
#pragma unroll
                for (int kf = 0; kf < 2; ++kf) {
                    int off = sk * 128 + kf * 64 + g * 8;
                    union { bf16x8 v; bf16x4 h4[2]; } vv;
                    vv.h4[0] = *(const bf16x4*)&V[vb + (off ^ sw2)];
                    vv.h4[1] = *(const bf16x4*)&V[vb + ((off + 32) ^ sw2)];
                    o[cth] = MFMA16(pk[kf].v, vv.v, o[cth]);
                }
            }
            __builtin_amdgcn_s_setprio(0);
        }
        __syncthreads();                 // all reads of this tile done
        if (more) {
#pragma unroll
            for (int p = 0; p < 4; ++p) *(bf16x8*)&lds[sdK[p]] = stK[p];
#pragma unroll
            for (int p = 0; p < 4; ++p) *(bf16x8*)&lds[sdV[p]] = stV[p];
            __syncthreads();             // next tile ready
        }
    }

    // ---- partials to LDS (oM overlays stage buffer; loop done) ----
#pragma unroll
    for (int cth = 0; cth < 4; ++cth)
#pragma unroll
        for (int reg = 0; reg < 4; ++reg)
            oMp[(((sq * 4 + sk) * 16) + g * 4 + reg) * 64 + cth * 16 + r] = o[cth][reg];
    if (lane < 16) {
        mM[sq][sk][lane] = m_;
        lM[sq][sk][lane] = l_;
    }
    __syncthreads();

    // ---- merge 4-way across sk; wave (sq,sk) takes rows sk*4+g ----
    {
        int rr = sk * 4 + g;
        float m0 = mM[sq][0][rr], m1 = mM[sq][1][rr], m2 = mM[sq][2][rr], m3 = mM[sq][3][rr];
        float M = fmaxf(fmaxf(m0, m1), fmaxf(m2, m3));
        float w0 = exp2fast(m0 - M), w1 = exp2fast(m1 - M);
        float w2 = exp2fast(m2 - M), w3 = exp2fast(m3 - M);
        float L = w0 * lM[sq][0][rr] + w1 * lM[sq][1][rr] + w2 * lM[sq][2][rr] + w3 * lM[sq][3][rr];
        float inv = 1.0f / L;
        int orow = b * Tn + q0 + sq * 16 + rr;
#pragma unroll
        for (int jj = 0; jj < 4; ++jj) {
            int col = r + 16 * jj;
            float val = w0 * oMp[((sq * 4 + 0) * 16 + rr) * 64 + col] +
                        w1 * oMp[((sq * 4 + 1) * 16 + rr) * 64 + col] +
                        w2 * oMp[((sq * 4 + 2) * 16 + rr) * 64 + col] +
                        w3 * oMp[((sq * 4 + 3) * 16 + rr) * 64 + col];
            out[orow * 64 + col] = val * inv;
        }
    }
}

extern "C" void kernel_launch(void* const* d_in, const int* in_sizes, int n_in,
                              void* d_out, int out_size, void* d_ws, size_t ws_size,
                              hipStream_t stream) {
    const float* x  = (const float*)d_in[0];
    const float* Wq = (const float*)d_in[1];
    const float* Wk = (const float*)d_in[2];
    const float* Wv = (const float*)d_in[3];
    float* out = (float*)d_out;
    char* ws = (char*)d_ws;

    unsigned short* Wo  = (unsigned short*)ws;                       // 192*512*2   = 196608 B
    unsigned short* q16 = (unsigned short*)(ws + 196608);            // 16384*64*2  = 2 MiB
    unsigned short* k16 = (unsigned short*)(ws + 196608 + 2097152);
    unsigned short* v16 = (unsigned short*)(ws + 196608 + 2 * 2097152);

    hipLaunchKernelGGL(wcvt, dim3(384), dim3(256), 0, stream, Wq, Wk, Wv, Wo);
    hipLaunchKernelGGL(proj, dim3(256), dim3(256), 0, stream, x, Wo, q16, k16, v16);
    hipLaunchKernelGGL(attn, dim3(512), dim3(512), 0, stream, q16, k16, v16, out);
}